// Round 1
// baseline (701.541 us; speedup 1.0000x reference)
//
#include <hip/hip_runtime.h>

#define T_LEN 512
#define B_SZ  64

__device__ __forceinline__ float sigf(float x) {
    return 1.0f / (1.0f + __expf(-x));
}
__device__ __forceinline__ float tanhf_(float x) {
    return 2.0f / (1.0f + __expf(-2.0f * x)) - 1.0f;
}

// ---------------- GEMM1: Z1 = gather(emb, tok) @ Wx1 + b1 ----------------
// Z1 layout: (T*B, 512), row r = t*64 + b, cols [fwd 256 | bwd 256]
__global__ __launch_bounds__(256) void gemm1_kernel(
    const int* __restrict__ tok, const float* __restrict__ emb,
    const float* __restrict__ w1f, const float* __restrict__ b1f,
    const float* __restrict__ w1b, const float* __restrict__ b1b,
    float* __restrict__ Z1)
{
    const int row0  = blockIdx.x * 64;
    const int dir   = blockIdx.y >> 2;
    const int nbase = (blockIdx.y & 3) * 64;
    const float* __restrict__ W    = dir ? w1b : w1f;
    const float* __restrict__ bias = dir ? b1b : b1f;

    __shared__ float As[64][20];
    __shared__ float Bs[20][64];
    __shared__ int   toks[64];

    const int tid = threadIdx.x;
    if (tid < 64) {
        int r = row0 + tid;
        int b = r & 63, t = r >> 6;
        toks[tid] = tok[b * T_LEN + t];
    }
    __syncthreads();

    float acc[4][4] = {};
    const int ty = tid >> 4, tx = tid & 15;

    for (int k0 = 0; k0 < 300; k0 += 20) {
        #pragma unroll
        for (int q = 0; q < 5; ++q) {
            int idx = tid + q * 256;
            int mm = idx / 20, kk = idx - mm * 20;
            As[mm][kk] = emb[(size_t)toks[mm] * 300 + (k0 + kk)];
            int kk2 = idx >> 6, nn = idx & 63;
            Bs[kk2][nn] = W[(k0 + kk2) * 256 + nbase + nn];
        }
        __syncthreads();
        #pragma unroll
        for (int kk = 0; kk < 20; ++kk) {
            float4 bv = *(const float4*)&Bs[kk][tx * 4];
            #pragma unroll
            for (int i = 0; i < 4; ++i) {
                float a = As[ty * 4 + i][kk];
                acc[i][0] = fmaf(a, bv.x, acc[i][0]);
                acc[i][1] = fmaf(a, bv.y, acc[i][1]);
                acc[i][2] = fmaf(a, bv.z, acc[i][2]);
                acc[i][3] = fmaf(a, bv.w, acc[i][3]);
            }
        }
        __syncthreads();
    }

    const float4 bvad = *(const float4*)&bias[nbase + tx * 4];
    #pragma unroll
    for (int i = 0; i < 4; ++i) {
        float4 o;
        o.x = acc[i][0] + bvad.x;
        o.y = acc[i][1] + bvad.y;
        o.z = acc[i][2] + bvad.z;
        o.w = acc[i][3] + bvad.w;
        *(float4*)&Z1[(size_t)(row0 + ty * 4 + i) * 512 + dir * 256 + nbase + tx * 4] = o;
    }
}

// ---------------- GEMM2: Z2 = H1 @ Wx2 + b2 ----------------
// H1: (T*B, 128) cols [fwd 64 | bwd 64]; Z2: (T*B, 256) cols [fwd 128 | bwd 128]
__global__ __launch_bounds__(256) void gemm2_kernel(
    const float* __restrict__ H1,
    const float* __restrict__ w2f, const float* __restrict__ b2f,
    const float* __restrict__ w2b, const float* __restrict__ b2b,
    float* __restrict__ Z2)
{
    const int row0  = blockIdx.x * 64;
    const int dir   = blockIdx.y >> 1;
    const int nbase = (blockIdx.y & 1) * 64;
    const float* __restrict__ W    = dir ? w2b : w2f;
    const float* __restrict__ bias = dir ? b2b : b2f;

    __shared__ float As[64][17];   // +1 pad: breaks 4-way bank conflict at stride 16
    __shared__ float Bs[16][64];

    const int tid = threadIdx.x;
    const int ty = tid >> 4, tx = tid & 15;
    float acc[4][4] = {};

    for (int k0 = 0; k0 < 128; k0 += 16) {
        #pragma unroll
        for (int q = 0; q < 4; ++q) {
            int idx = tid + q * 256;
            int mm = idx >> 4, kk = idx & 15;
            As[mm][kk] = H1[(size_t)(row0 + mm) * 128 + k0 + kk];
            int kk2 = idx >> 6, nn = idx & 63;
            Bs[kk2][nn] = W[(k0 + kk2) * 128 + nbase + nn];
        }
        __syncthreads();
        #pragma unroll
        for (int kk = 0; kk < 16; ++kk) {
            float4 bv = *(const float4*)&Bs[kk][tx * 4];
            #pragma unroll
            for (int i = 0; i < 4; ++i) {
                float a = As[ty * 4 + i][kk];
                acc[i][0] = fmaf(a, bv.x, acc[i][0]);
                acc[i][1] = fmaf(a, bv.y, acc[i][1]);
                acc[i][2] = fmaf(a, bv.z, acc[i][2]);
                acc[i][3] = fmaf(a, bv.w, acc[i][3]);
            }
        }
        __syncthreads();
    }

    const float4 bvad = *(const float4*)&bias[nbase + tx * 4];
    #pragma unroll
    for (int i = 0; i < 4; ++i) {
        float4 o;
        o.x = acc[i][0] + bvad.x;
        o.y = acc[i][1] + bvad.y;
        o.z = acc[i][2] + bvad.z;
        o.w = acc[i][3] + bvad.w;
        *(float4*)&Z2[(size_t)(row0 + ty * 4 + i) * 256 + dir * 128 + nbase + tx * 4] = o;
    }
}

// ---------------- LSTM layer 1 recurrence: one block per (batch, dir) ----------------
// Gates z = Zx(t) + h @ Wh; thread j owns output column j (gate j>>6, unit j&63).
__global__ __launch_bounds__(256) void lstm1_kernel(
    const float* __restrict__ Z1,
    const float* __restrict__ w1f, const float* __restrict__ w1b,
    float* __restrict__ H1)
{
    const int b   = blockIdx.x & 63;
    const int dir = blockIdx.x >> 6;
    const int j   = threadIdx.x;            // 0..255
    const int gate = j >> 6;
    const float* __restrict__ W = dir ? w1b : w1f;

    float wcol[64];                         // Wh column j, held in VGPRs
    #pragma unroll
    for (int u = 0; u < 64; ++u)
        wcol[u] = W[(300 + u) * 256 + j];

    __shared__ __align__(16) float h_lds[64];
    __shared__ float g_lds[256];

    float c = 0.0f;
    if (j < 64) h_lds[j] = 0.0f;
    __syncthreads();

    const float* __restrict__ zcol = Z1 + dir * 256 + j;
    const int t0 = dir ? (T_LEN - 1) : 0;
    float z_cur = zcol[(size_t)(t0 * 64 + b) * 512];

    for (int s = 0; s < T_LEN; ++s) {
        const int t  = dir ? (T_LEN - 1 - s) : s;
        const int s2 = (s + 1 < T_LEN) ? (s + 1) : s;
        const int t2 = dir ? (T_LEN - 1 - s2) : s2;
        float z_next = zcol[(size_t)(t2 * 64 + b) * 512];  // prefetch next step

        const float4* h4 = (const float4*)h_lds;
        float a0 = 0.f, a1 = 0.f, a2 = 0.f, a3 = 0.f;
        #pragma unroll
        for (int q = 0; q < 16; ++q) {
            float4 hv = h4[q];
            a0 = fmaf(hv.x, wcol[4 * q + 0], a0);
            a1 = fmaf(hv.y, wcol[4 * q + 1], a1);
            a2 = fmaf(hv.z, wcol[4 * q + 2], a2);
            a3 = fmaf(hv.w, wcol[4 * q + 3], a3);
        }
        float zz = z_cur + ((a0 + a1) + (a2 + a3));
        float act = (gate == 2) ? tanhf_(zz) : sigf(zz);
        g_lds[j] = act;
        __syncthreads();
        if (j < 64) {
            float f  = g_lds[j];
            float ii = g_lds[64 + j];
            float gg = g_lds[128 + j];
            float oo = g_lds[192 + j];
            c = fmaf(f, c, ii * gg);
            float hn = oo * tanhf_(c);
            h_lds[j] = hn;
            H1[(size_t)(t * 64 + b) * 128 + dir * 64 + j] = hn;
        }
        __syncthreads();
        z_cur = z_next;
    }
}

// ---------------- LSTM layer 2 recurrence (final state only) ----------------
__global__ __launch_bounds__(128) void lstm2_kernel(
    const float* __restrict__ Z2,
    const float* __restrict__ w2f, const float* __restrict__ w2b,
    float* __restrict__ H2)
{
    const int b   = blockIdx.x & 63;
    const int dir = blockIdx.x >> 6;
    const int j   = threadIdx.x;            // 0..127
    const int gate = j >> 5;
    const float* __restrict__ W = dir ? w2b : w2f;

    float wcol[32];
    #pragma unroll
    for (int u = 0; u < 32; ++u)
        wcol[u] = W[(128 + u) * 128 + j];

    __shared__ __align__(16) float h_lds[32];
    __shared__ float g_lds[128];

    float c = 0.0f, hlast = 0.0f;
    if (j < 32) h_lds[j] = 0.0f;
    __syncthreads();

    const float* __restrict__ zcol = Z2 + dir * 128 + j;
    const int t0 = dir ? (T_LEN - 1) : 0;
    float z_cur = zcol[(size_t)(t0 * 64 + b) * 256];

    for (int s = 0; s < T_LEN; ++s) {
        const int s2 = (s + 1 < T_LEN) ? (s + 1) : s;
        const int t2 = dir ? (T_LEN - 1 - s2) : s2;
        float z_next = zcol[(size_t)(t2 * 64 + b) * 256];

        const float4* h4 = (const float4*)h_lds;
        float a0 = 0.f, a1 = 0.f, a2 = 0.f, a3 = 0.f;
        #pragma unroll
        for (int q = 0; q < 8; ++q) {
            float4 hv = h4[q];
            a0 = fmaf(hv.x, wcol[4 * q + 0], a0);
            a1 = fmaf(hv.y, wcol[4 * q + 1], a1);
            a2 = fmaf(hv.z, wcol[4 * q + 2], a2);
            a3 = fmaf(hv.w, wcol[4 * q + 3], a3);
        }
        float zz = z_cur + ((a0 + a1) + (a2 + a3));
        float act = (gate == 2) ? tanhf_(zz) : sigf(zz);
        g_lds[j] = act;
        __syncthreads();
        if (j < 32) {
            float f  = g_lds[j];
            float ii = g_lds[32 + j];
            float gg = g_lds[64 + j];
            float oo = g_lds[96 + j];
            c = fmaf(f, c, ii * gg);
            hlast = oo * tanhf_(c);
            h_lds[j] = hlast;
        }
        __syncthreads();
        z_cur = z_next;
    }
    if (j < 32) H2[b * 64 + dir * 32 + j] = hlast;
}

// ---------------- Dense head: relu(h2 @ wd + bd) @ wo + bo -> sigmoid ----------------
__global__ __launch_bounds__(256) void head_kernel(
    const float* __restrict__ H2,
    const float* __restrict__ wd, const float* __restrict__ bd,
    const float* __restrict__ wo, const float* __restrict__ bo,
    float* __restrict__ out)
{
    const int tid = threadIdx.x;
    const int b = tid >> 2, qd = tid & 3;    // 4 threads per batch row

    float hv[64];
    #pragma unroll
    for (int u = 0; u < 64; ++u) hv[u] = H2[b * 64 + u];

    float part = 0.0f;
    #pragma unroll
    for (int iq = 0; iq < 8; ++iq) {
        int i = qd * 8 + iq;
        float a = bd[i];
        #pragma unroll
        for (int u = 0; u < 64; ++u)
            a = fmaf(hv[u], wd[u * 32 + i], a);
        a = fmaxf(a, 0.0f);
        part = fmaf(a, wo[i], part);
    }

    __shared__ float ps[256];
    ps[tid] = part;
    __syncthreads();
    if (qd == 0) {
        float s = ps[tid] + ps[tid + 1] + ps[tid + 2] + ps[tid + 3];
        out[b] = sigf(s + bo[0]);
    }
}

extern "C" void kernel_launch(void* const* d_in, const int* in_sizes, int n_in,
                              void* d_out, int out_size, void* d_ws, size_t ws_size,
                              hipStream_t stream)
{
    const int*   tok = (const int*)  d_in[0];
    const float* emb = (const float*)d_in[1];
    const float* w1f = (const float*)d_in[2];
    const float* b1f = (const float*)d_in[3];
    const float* w1b = (const float*)d_in[4];
    const float* b1b = (const float*)d_in[5];
    const float* w2f = (const float*)d_in[6];
    const float* b2f = (const float*)d_in[7];
    const float* w2b = (const float*)d_in[8];
    const float* b2b = (const float*)d_in[9];
    const float* wd  = (const float*)d_in[10];
    const float* bd  = (const float*)d_in[11];
    const float* wo  = (const float*)d_in[12];
    const float* bo  = (const float*)d_in[13];
    float* out = (float*)d_out;

    // Workspace layout (fp32):
    //   Z1: 32768 x 512  (67.1 MB)   gate pre-activations, layer 1 (both dirs)
    //   H1: 32768 x 128  (16.8 MB)   layer-1 output sequence
    //   H2: 64 x 64                  layer-2 final states
    //   Z2 aliases Z1 (Z1 dead after lstm1): 32768 x 256
    float* Z1 = (float*)d_ws;
    float* H1 = Z1 + (size_t)32768 * 512;
    float* H2 = H1 + (size_t)32768 * 128;
    float* Z2 = Z1;

    gemm1_kernel<<<dim3(512, 8), 256, 0, stream>>>(tok, emb, w1f, b1f, w1b, b1b, Z1);
    lstm1_kernel<<<128, 256, 0, stream>>>(Z1, w1f, w1b, H1);
    gemm2_kernel<<<dim3(512, 4), 256, 0, stream>>>(H1, w2f, b2f, w2b, b2b, Z2);
    lstm2_kernel<<<128, 128, 0, stream>>>(Z2, w2f, w2b, H2);
    head_kernel<<<1, 256, 0, stream>>>(H2, wd, bd, wo, bo, out);
}